// Round 1
// baseline (5242.814 us; speedup 1.0000x reference)
//
#include <hip/hip_runtime.h>
#include <hip/hip_bf16.h>
#include <cstddef>

// Problem constants (B,H,W,C)=(4,96,96,256), G=4, K=3
#define B_   4
#define H_   96
#define W_   96
#define C_   256
#define G_   4
#define CG   64      // C/G
#define NPOS 9       // K*K
#define KC   576     // K*K*CG
#define HW   (H_*W_)      // 9216
#define NPIX (B_*H_*W_)   // 36864

// ---------------------------------------------------------------------------
// K0: transpose w_off [G][3][3][CG][18] -> wt [G][18][9][CG] (coalesced lanes)
// ---------------------------------------------------------------------------
__global__ void k_transpose_woff(const float* __restrict__ w_off,
                                 float* __restrict__ wt) {
    int idx = blockIdx.x * 256 + threadIdx.x;
    const int total = G_ * 18 * NPOS * CG;
    if (idx >= total) return;
    int c = idx & 63;
    int r = idx >> 6;             // g*18*9 + oc*9 + nbr
    int nbr = r % NPOS; r /= NPOS;
    int oc  = r % 18;
    int g   = r / 18;
    wt[idx] = w_off[((size_t)(g * NPOS + nbr) * CG + c) * 18 + oc];
}

// ---------------------------------------------------------------------------
// K1: init 1x1 conv = GEMM  y[px][co] = x[px][:] @ w_init[:][co] + b_init[co]
// Tile 64 px x 64 co, K=256 in chunks of 64. 256 threads, 4x4 regs each.
// ---------------------------------------------------------------------------
__global__ void __launch_bounds__(256) k_gemm_init(
        const float* __restrict__ A, const float* __restrict__ Wm,
        const float* __restrict__ bias, float* __restrict__ Cout) {
    __shared__ __align__(16) float at[64][68];
    __shared__ __align__(16) float wt_[64][68];
    int t  = threadIdx.x;
    int px0 = blockIdx.x * 64;
    int n0  = blockIdx.y * 64;
    int tp = t >> 4, tf = t & 15;
    int lr = t >> 6, lc = t & 63;
    float acc[4][4] = {};
    for (int kk = 0; kk < C_; kk += 64) {
        #pragma unroll
        for (int i = 0; i < 16; i++) {
            int r = lr + i * 4;
            at [r][lc] = A [(size_t)(px0 + r) * C_ + kk + lc];
            wt_[r][lc] = Wm[(size_t)(kk  + r) * C_ + n0 + lc];
        }
        __syncthreads();
        #pragma unroll 8
        for (int k = 0; k < 64; k++) {
            float4 bv = *(const float4*)&wt_[k][tf * 4];
            float a0 = at[tp*4+0][k], a1 = at[tp*4+1][k];
            float a2 = at[tp*4+2][k], a3 = at[tp*4+3][k];
            acc[0][0] += a0*bv.x; acc[0][1] += a0*bv.y; acc[0][2] += a0*bv.z; acc[0][3] += a0*bv.w;
            acc[1][0] += a1*bv.x; acc[1][1] += a1*bv.y; acc[1][2] += a1*bv.z; acc[1][3] += a1*bv.w;
            acc[2][0] += a2*bv.x; acc[2][1] += a2*bv.y; acc[2][2] += a2*bv.z; acc[2][3] += a2*bv.w;
            acc[3][0] += a3*bv.x; acc[3][1] += a3*bv.y; acc[3][2] += a3*bv.z; acc[3][3] += a3*bv.w;
        }
        __syncthreads();
    }
    float4 bb = *(const float4*)&bias[n0 + tf * 4];
    #pragma unroll
    for (int pi = 0; pi < 4; pi++) {
        int px = px0 + tp * 4 + pi;
        float4 v = make_float4(acc[pi][0] + bb.x, acc[pi][1] + bb.y,
                               acc[pi][2] + bb.z, acc[pi][3] + bb.w);
        *(float4*)&Cout[(size_t)px * C_ + n0 + tf * 4] = v;
    }
}

// ---------------------------------------------------------------------------
// K2: offsets 3x3 conv (64 -> 18) for one group.
// Wave-per-pixel, lane = input channel; transposed weights staged in LDS;
// 64-lane shfl_xor reductions for the 18 outputs. Zero-padded 'SAME'.
// ---------------------------------------------------------------------------
__global__ void __launch_bounds__(256) k_offconv(
        const float* __restrict__ y, const float* __restrict__ wt_g,
        const float* __restrict__ boff_g, float* __restrict__ off, int g) {
    __shared__ float ws_[18 * NPOS * CG];   // 41.5 KB
    for (int i = threadIdx.x; i < 18 * NPOS * CG; i += 256) ws_[i] = wt_g[i];
    __syncthreads();
    int lane = threadIdx.x & 63;
    float bo = boff_g[lane < 18 ? lane : 0];
    int wv = blockIdx.x * 4 + (threadIdx.x >> 6);
    for (int px = wv; px < NPIX; px += 4096) {
        int b = px / HW; int rem = px - b * HW;
        int yy = rem / W_; int xx = rem - yy * W_;
        float partial[18];
        #pragma unroll
        for (int oc = 0; oc < 18; oc++) partial[oc] = 0.f;
        const float* yb = y + (size_t)b * HW * C_ + g * CG + lane;
        for (int di = 0; di < 3; di++) {
            int ny = yy + di - 1; if ((unsigned)ny >= H_) continue;
            for (int dj = 0; dj < 3; dj++) {
                int nx = xx + dj - 1; if ((unsigned)nx >= W_) continue;
                float yv = yb[(size_t)(ny * W_ + nx) * C_];
                int nbr = di * 3 + dj;
                #pragma unroll
                for (int oc = 0; oc < 18; oc++)
                    partial[oc] += yv * ws_[(oc * NPOS + nbr) * CG + lane];
            }
        }
        float res = 0.f;
        #pragma unroll
        for (int oc = 0; oc < 18; oc++) {
            float v = partial[oc];
            #pragma unroll
            for (int s = 32; s >= 1; s >>= 1) v += __shfl_xor(v, s, 64);
            if (lane == oc) res = v;
        }
        if (lane < 18) off[(size_t)px * 18 + lane] = res + bo;
    }
}

// ---------------------------------------------------------------------------
// K3: deformable bilinear sampling for one group.
// One wave per (pixel, kernel position p); lane = channel c.
// smp[px][p*64+c] layout matches the reference's k*k*Cg channel order.
// Edge semantics match reference: clip(loc), floor, min(x0+1, W-1) --
// a location clipped to the high edge gets zero weight automatically.
// ---------------------------------------------------------------------------
__global__ void __launch_bounds__(256) k_sample(
        const float* __restrict__ y, const float* __restrict__ off,
        float* __restrict__ smp, int g) {
    int wid  = blockIdx.x * 4 + (threadIdx.x >> 6);
    int lane = threadIdx.x & 63;
    int px = wid / 9, p = wid - px * 9;
    int b = px / HW; int rem = px - b * HW;
    int yy = rem / W_; int xx = rem - yy * W_;
    float ox = off[(size_t)px * 18 + 2 * p];
    float oy = off[(size_t)px * 18 + 2 * p + 1];
    int di = p / 3, dj = p - di * 3;
    float lx = (float)xx + (float)(dj - 1) + ox;
    float ly = (float)yy + (float)(di - 1) + oy;
    lx = fminf(fmaxf(lx, 0.f), (float)(W_ - 1));
    ly = fminf(fmaxf(ly, 0.f), (float)(H_ - 1));
    float x0f = floorf(lx), y0f = floorf(ly);
    float x1f = fminf(x0f + 1.f, (float)(W_ - 1));
    float y1f = fminf(y0f + 1.f, (float)(H_ - 1));
    float wa = (x1f - lx) * (y1f - ly);
    float wb = (x1f - lx) * (ly - y0f);
    float wc = (lx - x0f) * (y1f - ly);
    float wd = (lx - x0f) * (ly - y0f);
    int ix0 = (int)x0f, iy0 = (int)y0f, ix1 = (int)x1f, iy1 = (int)y1f;
    const float* base = y + (size_t)b * HW * C_ + g * CG + lane;
    float Ia = base[(size_t)(iy0 * W_ + ix0) * C_];
    float Ib = base[(size_t)(iy1 * W_ + ix0) * C_];
    float Ic = base[(size_t)(iy0 * W_ + ix1) * C_];
    float Id = base[(size_t)(iy1 * W_ + ix1) * C_];
    smp[(size_t)px * KC + p * CG + lane] = wa * Ia + wb * Ib + wc * Ic + wd * Id;
}

// ---------------------------------------------------------------------------
// K4: fused depthwise-3x3 + pointwise (576 -> 64) GEMM for one group.
// Block = 64 px x 64 out-features; K=576 in 9 chunks of 64 (one kernel
// position per chunk). The depthwise A-tile is computed on the fly into LDS
// (9 coalesced smp reads per element, zero-padded 'SAME'), so h is never
// materialized in global memory.
// ---------------------------------------------------------------------------
__global__ void __launch_bounds__(256) k_dwpw(
        const float* __restrict__ smp, const float* __restrict__ w_dw_g,
        const float* __restrict__ b_dw_g, const float* __restrict__ w_pw_g,
        const float* __restrict__ b_pw_g, float* __restrict__ out, int g) {
    __shared__ __align__(16) float ht [64][68];
    __shared__ __align__(16) float wt_[64][68];
    int t = threadIdx.x;
    int px0 = blockIdx.x * 64;
    int tp = t >> 4, tf = t & 15;
    int lr = t >> 6, lc = t & 63;
    float acc[4][4] = {};
    for (int p = 0; p < 9; p++) {
        int kk = p * 64;
        // stage W chunk [64 k][64 f]
        #pragma unroll
        for (int i = 0; i < 16; i++) {
            int r = lr + i * 4;
            wt_[r][lc] = w_pw_g[(size_t)(kk + r) * 64 + lc];
        }
        // build depthwise A chunk [64 px][64 o]
        int o = kk + lc;
        float bdw = b_dw_g[o];
        #pragma unroll
        for (int i = 0; i < 16; i++) {
            int pxl = lr + i * 4;
            int px = px0 + pxl;
            int b = px / HW; int rem = px - b * HW;
            int yy = rem / W_; int xx = rem - yy * W_;
            float hv = bdw;
            #pragma unroll
            for (int di = 0; di < 3; di++) {
                int ny = yy + di - 1; if ((unsigned)ny >= H_) continue;
                #pragma unroll
                for (int dj = 0; dj < 3; dj++) {
                    int nx = xx + dj - 1; if ((unsigned)nx >= W_) continue;
                    int npx = (b * H_ + ny) * W_ + nx;
                    hv += smp[(size_t)npx * KC + o] * w_dw_g[(di * 3 + dj) * KC + o];
                }
            }
            ht[pxl][lc] = hv;
        }
        __syncthreads();
        #pragma unroll 8
        for (int k = 0; k < 64; k++) {
            float4 bv = *(const float4*)&wt_[k][tf * 4];
            float a0 = ht[tp*4+0][k], a1 = ht[tp*4+1][k];
            float a2 = ht[tp*4+2][k], a3 = ht[tp*4+3][k];
            acc[0][0] += a0*bv.x; acc[0][1] += a0*bv.y; acc[0][2] += a0*bv.z; acc[0][3] += a0*bv.w;
            acc[1][0] += a1*bv.x; acc[1][1] += a1*bv.y; acc[1][2] += a1*bv.z; acc[1][3] += a1*bv.w;
            acc[2][0] += a2*bv.x; acc[2][1] += a2*bv.y; acc[2][2] += a2*bv.z; acc[2][3] += a2*bv.w;
            acc[3][0] += a3*bv.x; acc[3][1] += a3*bv.y; acc[3][2] += a3*bv.z; acc[3][3] += a3*bv.w;
        }
        __syncthreads();
    }
    float4 bb = *(const float4*)&b_pw_g[tf * 4];
    #pragma unroll
    for (int pi = 0; pi < 4; pi++) {
        int px = px0 + tp * 4 + pi;
        float4 v = make_float4(acc[pi][0] + bb.x, acc[pi][1] + bb.y,
                               acc[pi][2] + bb.z, acc[pi][3] + bb.w);
        *(float4*)&out[(size_t)px * C_ + g * CG + tf * 4] = v;
    }
}

// ---------------------------------------------------------------------------
// ws layout (floats):
//   y   : NPIX*256            =  9,437,184   (37.7 MB)
//   wt  : G*18*9*64           =     41,472
//   off : NPIX*18             =    663,552   ( 2.7 MB, reused per group)
//   smp : NPIX*576            = 21,233,664   (84.9 MB, reused per group)
//   total ~ 125.5 MB
// ---------------------------------------------------------------------------
extern "C" void kernel_launch(void* const* d_in, const int* in_sizes, int n_in,
                              void* d_out, int out_size, void* d_ws, size_t ws_size,
                              hipStream_t stream) {
    const float* x      = (const float*)d_in[0];
    const float* w_init = (const float*)d_in[1];
    const float* b_init = (const float*)d_in[2];
    const float* w_off  = (const float*)d_in[3];
    const float* b_off  = (const float*)d_in[4];
    const float* w_dw   = (const float*)d_in[5];
    const float* b_dw   = (const float*)d_in[6];
    const float* w_pw   = (const float*)d_in[7];
    const float* b_pw   = (const float*)d_in[8];
    float* out = (float*)d_out;

    float* y   = (float*)d_ws;
    float* wt  = y   + (size_t)NPIX * C_;
    float* off = wt  + (size_t)G_ * 18 * NPOS * CG;
    float* smp = off + (size_t)NPIX * 18;

    k_transpose_woff<<<(G_ * 18 * NPOS * CG + 255) / 256, 256, 0, stream>>>(w_off, wt);
    k_gemm_init<<<dim3(NPIX / 64, C_ / 64), 256, 0, stream>>>(x, w_init, b_init, y);
    for (int g = 0; g < G_; g++) {
        k_offconv<<<1024, 256, 0, stream>>>(y, wt + (size_t)g * 18 * NPOS * CG,
                                            b_off + g * 18, off, g);
        k_sample<<<NPIX * NPOS / 4, 256, 0, stream>>>(y, off, smp, g);
        k_dwpw<<<NPIX / 64, 256, 0, stream>>>(smp,
                                              w_dw + (size_t)g * NPOS * KC,
                                              b_dw + (size_t)g * KC,
                                              w_pw + (size_t)g * KC * CG,
                                              b_pw + (size_t)g * CG,
                                              out, g);
    }
}

// Round 2
// 2534.573 us; speedup vs baseline: 2.0685x; 2.0685x over previous
//
#include <hip/hip_runtime.h>
#include <hip/hip_bf16.h>
#include <cstddef>

// Problem constants (B,H,W,C)=(4,96,96,256), G=4, K=3
#define B_   4
#define H_   96
#define W_   96
#define C_   256
#define G_   4
#define CG   64      // C/G
#define NPOS 9       // K*K
#define KC   576     // K*K*CG
#define HW   (H_*W_)      // 9216
#define NPIX (B_*H_*W_)   // 36864
#define WIN  258     // sample window rows per 64-px block: 64 + 2*(W+1)

// ---------------------------------------------------------------------------
// K0: transpose w_off [G][3][3][CG][18] -> wt [G][18][9][CG] (coalesced lanes)
// ---------------------------------------------------------------------------
__global__ void k_transpose_woff(const float* __restrict__ w_off,
                                 float* __restrict__ wt) {
    int idx = blockIdx.x * 256 + threadIdx.x;
    const int total = G_ * 18 * NPOS * CG;
    if (idx >= total) return;
    int c = idx & 63;
    int r = idx >> 6;             // g*18*9 + oc*9 + nbr
    int nbr = r % NPOS; r /= NPOS;
    int oc  = r % 18;
    int g   = r / 18;
    wt[idx] = w_off[((size_t)(g * NPOS + nbr) * CG + c) * 18 + oc];
}

// ---------------------------------------------------------------------------
// K1: init 1x1 conv = GEMM  y[px][co] = x[px][:] @ w_init[:][co] + b_init[co]
// ---------------------------------------------------------------------------
__global__ void __launch_bounds__(256) k_gemm_init(
        const float* __restrict__ A, const float* __restrict__ Wm,
        const float* __restrict__ bias, float* __restrict__ Cout) {
    __shared__ __align__(16) float at[64][68];
    __shared__ __align__(16) float wt_[64][68];
    int t  = threadIdx.x;
    int px0 = blockIdx.x * 64;
    int n0  = blockIdx.y * 64;
    int tp = t >> 4, tf = t & 15;
    int lr = t >> 6, lc = t & 63;
    float acc[4][4] = {};
    for (int kk = 0; kk < C_; kk += 64) {
        #pragma unroll
        for (int i = 0; i < 16; i++) {
            int r = lr + i * 4;
            at [r][lc] = A [(size_t)(px0 + r) * C_ + kk + lc];
            wt_[r][lc] = Wm[(size_t)(kk  + r) * C_ + n0 + lc];
        }
        __syncthreads();
        #pragma unroll 8
        for (int k = 0; k < 64; k++) {
            float4 bv = *(const float4*)&wt_[k][tf * 4];
            float a0 = at[tp*4+0][k], a1 = at[tp*4+1][k];
            float a2 = at[tp*4+2][k], a3 = at[tp*4+3][k];
            acc[0][0] += a0*bv.x; acc[0][1] += a0*bv.y; acc[0][2] += a0*bv.z; acc[0][3] += a0*bv.w;
            acc[1][0] += a1*bv.x; acc[1][1] += a1*bv.y; acc[1][2] += a1*bv.z; acc[1][3] += a1*bv.w;
            acc[2][0] += a2*bv.x; acc[2][1] += a2*bv.y; acc[2][2] += a2*bv.z; acc[2][3] += a2*bv.w;
            acc[3][0] += a3*bv.x; acc[3][1] += a3*bv.y; acc[3][2] += a3*bv.z; acc[3][3] += a3*bv.w;
        }
        __syncthreads();
    }
    float4 bb = *(const float4*)&bias[n0 + tf * 4];
    #pragma unroll
    for (int pi = 0; pi < 4; pi++) {
        int px = px0 + tp * 4 + pi;
        float4 v = make_float4(acc[pi][0] + bb.x, acc[pi][1] + bb.y,
                               acc[pi][2] + bb.z, acc[pi][3] + bb.w);
        *(float4*)&Cout[(size_t)px * C_ + n0 + tf * 4] = v;
    }
}

// ---------------------------------------------------------------------------
// K2: offsets 3x3 conv (64 -> 18), ALL groups (blockIdx.y = g).
// ---------------------------------------------------------------------------
__global__ void __launch_bounds__(256) k_offconv_all(
        const float* __restrict__ y, const float* __restrict__ wt,
        const float* __restrict__ b_off, float* __restrict__ off_all) {
    int g = blockIdx.y;
    const float* wt_g = wt + (size_t)g * 18 * NPOS * CG;
    __shared__ float ws_[18 * NPOS * CG];   // 41.5 KB
    for (int i = threadIdx.x; i < 18 * NPOS * CG; i += 256) ws_[i] = wt_g[i];
    __syncthreads();
    int lane = threadIdx.x & 63;
    float bo = b_off[g * 18 + (lane < 18 ? lane : 0)];
    int wv = blockIdx.x * 4 + (threadIdx.x >> 6);
    for (int px = wv; px < NPIX; px += 4096) {
        int b = px / HW; int rem = px - b * HW;
        int yy = rem / W_; int xx = rem - yy * W_;
        float partial[18];
        #pragma unroll
        for (int oc = 0; oc < 18; oc++) partial[oc] = 0.f;
        const float* yb = y + (size_t)b * HW * C_ + g * CG + lane;
        for (int di = 0; di < 3; di++) {
            int ny = yy + di - 1; if ((unsigned)ny >= H_) continue;
            for (int dj = 0; dj < 3; dj++) {
                int nx = xx + dj - 1; if ((unsigned)nx >= W_) continue;
                float yv = yb[(size_t)(ny * W_ + nx) * C_];
                int nbr = di * 3 + dj;
                #pragma unroll
                for (int oc = 0; oc < 18; oc++)
                    partial[oc] += yv * ws_[(oc * NPOS + nbr) * CG + lane];
            }
        }
        float res = 0.f;
        #pragma unroll
        for (int oc = 0; oc < 18; oc++) {
            float v = partial[oc];
            #pragma unroll
            for (int s = 32; s >= 1; s >>= 1) v += __shfl_xor(v, s, 64);
            if (lane == oc) res = v;
        }
        if (lane < 18) off_all[((size_t)g * NPIX + px) * 18 + lane] = res + bo;
    }
}

// ---------------------------------------------------------------------------
// K3: precompute bilinear weights + gather indices per (g, px, p).
// tab entry = 8 dwords: wa,wb,wc,wd (f32), ia,ib,ic,id (i32, element index
// into y including batch & group-channel base). Edge semantics = reference.
// ---------------------------------------------------------------------------
__global__ void __launch_bounds__(256) k_prep(
        const float* __restrict__ off_all, float* __restrict__ tab) {
    int tid = blockIdx.x * 256 + threadIdx.x;
    const int total = G_ * NPIX * NPOS;
    if (tid >= total) return;
    int p = tid % NPOS; int rem = tid / NPOS;   // rem = g*NPIX + px
    int px = rem % NPIX; int g = rem / NPIX;
    int b = px / HW; int r2 = px - b * HW;
    int yy = r2 / W_; int xx = r2 - yy * W_;
    float ox = off_all[(size_t)rem * 18 + 2 * p];
    float oy = off_all[(size_t)rem * 18 + 2 * p + 1];
    int di = p / 3, dj = p - di * 3;
    float lx = (float)(xx + dj - 1) + ox;
    float ly = (float)(yy + di - 1) + oy;
    lx = fminf(fmaxf(lx, 0.f), (float)(W_ - 1));
    ly = fminf(fmaxf(ly, 0.f), (float)(H_ - 1));
    float x0f = floorf(lx), y0f = floorf(ly);
    float x1f = fminf(x0f + 1.f, (float)(W_ - 1));
    float y1f = fminf(y0f + 1.f, (float)(H_ - 1));
    float wa = (x1f - lx) * (y1f - ly);
    float wb = (x1f - lx) * (ly - y0f);
    float wc = (lx - x0f) * (y1f - ly);
    float wd = (lx - x0f) * (ly - y0f);
    int ix0 = (int)x0f, iy0 = (int)y0f, ix1 = (int)x1f, iy1 = (int)y1f;
    int base = b * HW * C_ + g * CG;
    int ia = base + (iy0 * W_ + ix0) * C_;
    int ib = base + (iy1 * W_ + ix0) * C_;
    int ic = base + (iy0 * W_ + ix1) * C_;
    int id = base + (iy1 * W_ + ix1) * C_;
    float* tp8 = tab + (size_t)tid * 8;
    *(float4*)tp8 = make_float4(wa, wb, wc, wd);
    int4 iv = make_int4(ia, ib, ic, id);
    *(float4*)(tp8 + 4) = *(float4*)&iv;
}

// ---------------------------------------------------------------------------
// K4: fused sample + depthwise-3x3 + pointwise GEMM, ALL groups.
// Block = (64 px x 64 out-features) for group blockIdx.y.
// Per K-chunk p: waves cooperatively sample the 258-row window from y
// (4 gathers/row, all cache-hot) into bf16 LDS; each thread then combines
// 9 taps from LDS into the depthwise value, then the 64-wide GEMM chunk.
// ---------------------------------------------------------------------------
__global__ void __launch_bounds__(256) k_dwpw_all(
        const float* __restrict__ y, const float* __restrict__ tab,
        const float* __restrict__ w_dw, const float* __restrict__ b_dw,
        const float* __restrict__ w_pw, const float* __restrict__ b_pw,
        float* __restrict__ out) {
    __shared__ __hip_bfloat16 swin[WIN][64];       // 33.0 KB
    __shared__ __align__(16) float ht [64][68];    // 17.4 KB
    __shared__ __align__(16) float wt_[64][68];    // 17.4 KB
    int g = blockIdx.y;
    int px0 = blockIdx.x * 64;
    int t = threadIdx.x;
    int lane = t & 63, wv = t >> 6;
    int tp = t >> 4, tf = t & 15;
    const float* wdwg = w_dw + (size_t)g * NPOS * KC;
    const float* bdwg = b_dw + (size_t)g * KC;
    const float* wpwg = w_pw + (size_t)g * KC * CG;
    const float* bpwg = b_pw + (size_t)g * CG;
    const float* tabg = tab + (size_t)g * NPIX * NPOS * 8;

    // per-i edge nibbles: bit0 yy==0, bit1 yy==H-1, bit2 xx==0, bit3 xx==W-1
    unsigned long long edges = 0ull;
    #pragma unroll
    for (int i = 0; i < 16; i++) {
        int px = px0 + wv + i * 4;
        int b = px / HW; int r2 = px - b * HW;
        int yy = r2 / W_; int xx = r2 - yy * W_;
        unsigned e = (yy == 0) | ((yy == H_ - 1) << 1)
                   | ((xx == 0) << 2) | ((xx == W_ - 1) << 3);
        edges |= ((unsigned long long)e) << (4 * i);
    }

    float acc[4][4] = {};
    for (int p = 0; p < NPOS; p++) {
        // stage pointwise-W chunk [64 k][64 f]
        #pragma unroll
        for (int i = 0; i < 16; i++) {
            int r = wv + i * 4;
            wt_[r][lane] = wpwg[(size_t)(p * 64 + r) * 64 + lane];
        }
        // build bf16 sample window
        for (int r = wv; r < WIN; r += 4) {
            int npx = px0 - (W_ + 1) + r;
            if ((unsigned)npx < (unsigned)NPIX) {
                const float* e = tabg + ((size_t)npx * NPOS + p) * 8;
                float4 w4 = *(const float4*)e;
                const int* ei = (const int*)(e + 4);
                float s = w4.x * y[ei[0] + lane] + w4.y * y[ei[1] + lane]
                        + w4.z * y[ei[2] + lane] + w4.w * y[ei[3] + lane];
                swin[r][lane] = __float2bfloat16(s);
            }
        }
        __syncthreads();
        // depthwise combine -> ht
        int o = p * 64 + lane;
        float wd9[9];
        #pragma unroll
        for (int tap = 0; tap < 9; tap++) wd9[tap] = wdwg[tap * KC + o];
        float bd = bdwg[o];
        #pragma unroll
        for (int i = 0; i < 16; i++) {
            int pxl = wv + i * 4;
            unsigned e = (unsigned)(edges >> (4 * i)) & 15u;
            float hv = bd;
            #pragma unroll
            for (int di = 0; di < 3; di++) {
                if ((di == 0 && (e & 1u)) || (di == 2 && (e & 2u))) continue;
                #pragma unroll
                for (int dj = 0; dj < 3; dj++) {
                    if ((dj == 0 && (e & 4u)) || (dj == 2 && (e & 8u))) continue;
                    int r = pxl + (W_ + 1) + (di - 1) * W_ + (dj - 1);
                    hv += __bfloat162float(swin[r][lane]) * wd9[di * 3 + dj];
                }
            }
            ht[pxl][lane] = hv;
        }
        __syncthreads();
        // GEMM chunk
        #pragma unroll 8
        for (int k = 0; k < 64; k++) {
            float4 bv = *(const float4*)&wt_[k][tf * 4];
            float a0 = ht[tp*4+0][k], a1 = ht[tp*4+1][k];
            float a2 = ht[tp*4+2][k], a3 = ht[tp*4+3][k];
            acc[0][0] += a0*bv.x; acc[0][1] += a0*bv.y; acc[0][2] += a0*bv.z; acc[0][3] += a0*bv.w;
            acc[1][0] += a1*bv.x; acc[1][1] += a1*bv.y; acc[1][2] += a1*bv.z; acc[1][3] += a1*bv.w;
            acc[2][0] += a2*bv.x; acc[2][1] += a2*bv.y; acc[2][2] += a2*bv.z; acc[2][3] += a2*bv.w;
            acc[3][0] += a3*bv.x; acc[3][1] += a3*bv.y; acc[3][2] += a3*bv.z; acc[3][3] += a3*bv.w;
        }
        __syncthreads();
    }
    float4 bb = *(const float4*)&bpwg[tf * 4];
    #pragma unroll
    for (int pi = 0; pi < 4; pi++) {
        int px = px0 + tp * 4 + pi;
        float4 v = make_float4(acc[pi][0] + bb.x, acc[pi][1] + bb.y,
                               acc[pi][2] + bb.z, acc[pi][3] + bb.w);
        *(float4*)&out[(size_t)px * C_ + g * CG + tf * 4] = v;
    }
}

// ---------------------------------------------------------------------------
// ws layout (floats):
//   y       : NPIX*256        =  9,437,184   (37.7 MB)
//   wt      : G*18*9*64       =     41,472
//   off_all : G*NPIX*18       =  2,654,208   (10.6 MB)
//   tab     : G*NPIX*9*8      = 10,616,832   (42.5 MB)
//   total ~ 91 MB
// ---------------------------------------------------------------------------
extern "C" void kernel_launch(void* const* d_in, const int* in_sizes, int n_in,
                              void* d_out, int out_size, void* d_ws, size_t ws_size,
                              hipStream_t stream) {
    const float* x      = (const float*)d_in[0];
    const float* w_init = (const float*)d_in[1];
    const float* b_init = (const float*)d_in[2];
    const float* w_off  = (const float*)d_in[3];
    const float* b_off  = (const float*)d_in[4];
    const float* w_dw   = (const float*)d_in[5];
    const float* b_dw   = (const float*)d_in[6];
    const float* w_pw   = (const float*)d_in[7];
    const float* b_pw   = (const float*)d_in[8];
    float* out = (float*)d_out;

    float* y       = (float*)d_ws;
    float* wt      = y       + (size_t)NPIX * C_;
    float* off_all = wt      + (size_t)G_ * 18 * NPOS * CG;
    float* tab     = off_all + (size_t)G_ * NPIX * 18;

    k_transpose_woff<<<(G_ * 18 * NPOS * CG + 255) / 256, 256, 0, stream>>>(w_off, wt);
    k_gemm_init<<<dim3(NPIX / 64, C_ / 64), 256, 0, stream>>>(x, w_init, b_init, y);
    k_offconv_all<<<dim3(1024, G_), 256, 0, stream>>>(y, wt, b_off, off_all);
    k_prep<<<(G_ * NPIX * NPOS + 255) / 256, 256, 0, stream>>>(off_all, tab);
    k_dwpw_all<<<dim3(NPIX / 64, G_), 256, 0, stream>>>(y, tab, w_dw, b_dw,
                                                        w_pw, b_pw, out);
}

// Round 3
// 718.208 us; speedup vs baseline: 7.2999x; 3.5290x over previous
//
#include <hip/hip_runtime.h>
#include <hip/hip_bf16.h>
#include <cstddef>

// Problem constants (B,H,W,C)=(4,96,96,256), G=4, K=3
#define B_   4
#define H_   96
#define W_   96
#define C_   256
#define G_   4
#define CG   64      // C/G
#define NPOS 9       // K*K
#define KC   576     // K*K*CG
#define HW   (H_*W_)      // 9216
#define NPIX (B_*H_*W_)   // 36864

// 2-D pixel tile for the fused kernel
#define TM 4
#define TN 16
#define WR 6          // TM+2
#define WC 18         // TN+2
#define WPOS 108      // WR*WC

// ---------------------------------------------------------------------------
// K0: transpose w_off [G][3][3][CG][18] -> wt [G][18][9][CG]
// ---------------------------------------------------------------------------
__global__ void k_transpose_woff(const float* __restrict__ w_off,
                                 float* __restrict__ wt) {
    int idx = blockIdx.x * 256 + threadIdx.x;
    const int total = G_ * 18 * NPOS * CG;
    if (idx >= total) return;
    int c = idx & 63;
    int r = idx >> 6;
    int nbr = r % NPOS; r /= NPOS;
    int oc  = r % 18;
    int g   = r / 18;
    wt[idx] = w_off[((size_t)(g * NPOS + nbr) * CG + c) * 18 + oc];
}

// ---------------------------------------------------------------------------
// K1: init 1x1 conv = GEMM
// ---------------------------------------------------------------------------
__global__ void __launch_bounds__(256) k_gemm_init(
        const float* __restrict__ A, const float* __restrict__ Wm,
        const float* __restrict__ bias, float* __restrict__ Cout) {
    __shared__ __align__(16) float at[64][68];
    __shared__ __align__(16) float wt_[64][68];
    int t  = threadIdx.x;
    int px0 = blockIdx.x * 64;
    int n0  = blockIdx.y * 64;
    int tp = t >> 4, tf = t & 15;
    int lr = t >> 6, lc = t & 63;
    float acc[4][4] = {};
    for (int kk = 0; kk < C_; kk += 64) {
        #pragma unroll
        for (int i = 0; i < 16; i++) {
            int r = lr + i * 4;
            at [r][lc] = A [(size_t)(px0 + r) * C_ + kk + lc];
            wt_[r][lc] = Wm[(size_t)(kk  + r) * C_ + n0 + lc];
        }
        __syncthreads();
        #pragma unroll 8
        for (int k = 0; k < 64; k++) {
            float4 bv = *(const float4*)&wt_[k][tf * 4];
            float a0 = at[tp*4+0][k], a1 = at[tp*4+1][k];
            float a2 = at[tp*4+2][k], a3 = at[tp*4+3][k];
            acc[0][0] += a0*bv.x; acc[0][1] += a0*bv.y; acc[0][2] += a0*bv.z; acc[0][3] += a0*bv.w;
            acc[1][0] += a1*bv.x; acc[1][1] += a1*bv.y; acc[1][2] += a1*bv.z; acc[1][3] += a1*bv.w;
            acc[2][0] += a2*bv.x; acc[2][1] += a2*bv.y; acc[2][2] += a2*bv.z; acc[2][3] += a2*bv.w;
            acc[3][0] += a3*bv.x; acc[3][1] += a3*bv.y; acc[3][2] += a3*bv.z; acc[3][3] += a3*bv.w;
        }
        __syncthreads();
    }
    float4 bb = *(const float4*)&bias[n0 + tf * 4];
    #pragma unroll
    for (int pi = 0; pi < 4; pi++) {
        int px = px0 + tp * 4 + pi;
        float4 v = make_float4(acc[pi][0] + bb.x, acc[pi][1] + bb.y,
                               acc[pi][2] + bb.z, acc[pi][3] + bb.w);
        *(float4*)&Cout[(size_t)px * C_ + n0 + tf * 4] = v;
    }
}

// ---------------------------------------------------------------------------
// K2: offsets 3x3 conv (64 -> 18), ALL groups (blockIdx.y = g).
// ---------------------------------------------------------------------------
__global__ void __launch_bounds__(256) k_offconv_all(
        const float* __restrict__ y, const float* __restrict__ wt,
        const float* __restrict__ b_off, float* __restrict__ off_all) {
    int g = blockIdx.y;
    const float* wt_g = wt + (size_t)g * 18 * NPOS * CG;
    __shared__ float ws_[18 * NPOS * CG];
    for (int i = threadIdx.x; i < 18 * NPOS * CG; i += 256) ws_[i] = wt_g[i];
    __syncthreads();
    int lane = threadIdx.x & 63;
    float bo = b_off[g * 18 + (lane < 18 ? lane : 0)];
    int wv = blockIdx.x * 4 + (threadIdx.x >> 6);
    for (int px = wv; px < NPIX; px += 4096) {
        int b = px / HW; int rem = px - b * HW;
        int yy = rem / W_; int xx = rem - yy * W_;
        float partial[18];
        #pragma unroll
        for (int oc = 0; oc < 18; oc++) partial[oc] = 0.f;
        const float* yb = y + (size_t)b * HW * C_ + g * CG + lane;
        for (int di = 0; di < 3; di++) {
            int ny = yy + di - 1; if ((unsigned)ny >= H_) continue;
            for (int dj = 0; dj < 3; dj++) {
                int nx = xx + dj - 1; if ((unsigned)nx >= W_) continue;
                float yv = yb[(size_t)(ny * W_ + nx) * C_];
                int nbr = di * 3 + dj;
                #pragma unroll
                for (int oc = 0; oc < 18; oc++)
                    partial[oc] += yv * ws_[(oc * NPOS + nbr) * CG + lane];
            }
        }
        float res = 0.f;
        #pragma unroll
        for (int oc = 0; oc < 18; oc++) {
            float v = partial[oc];
            #pragma unroll
            for (int s = 32; s >= 1; s >>= 1) v += __shfl_xor(v, s, 64);
            if (lane == oc) res = v;
        }
        if (lane < 18) off_all[((size_t)g * NPIX + px) * 18 + lane] = res + bo;
    }
}

// ---------------------------------------------------------------------------
// K3: precompute bilinear weights + gather indices per (g, px, p).
// ---------------------------------------------------------------------------
__global__ void __launch_bounds__(256) k_prep(
        const float* __restrict__ off_all, float* __restrict__ tab) {
    int tid = blockIdx.x * 256 + threadIdx.x;
    const int total = G_ * NPIX * NPOS;
    if (tid >= total) return;
    int p = tid % NPOS; int rem = tid / NPOS;
    int px = rem % NPIX; int g = rem / NPIX;
    int b = px / HW; int r2 = px - b * HW;
    int yy = r2 / W_; int xx = r2 - yy * W_;
    float ox = off_all[(size_t)rem * 18 + 2 * p];
    float oy = off_all[(size_t)rem * 18 + 2 * p + 1];
    int di = p / 3, dj = p - di * 3;
    float lx = (float)(xx + dj - 1) + ox;
    float ly = (float)(yy + di - 1) + oy;
    lx = fminf(fmaxf(lx, 0.f), (float)(W_ - 1));
    ly = fminf(fmaxf(ly, 0.f), (float)(H_ - 1));
    float x0f = floorf(lx), y0f = floorf(ly);
    float x1f = fminf(x0f + 1.f, (float)(W_ - 1));
    float y1f = fminf(y0f + 1.f, (float)(H_ - 1));
    float wa = (x1f - lx) * (y1f - ly);
    float wb = (x1f - lx) * (ly - y0f);
    float wc = (lx - x0f) * (y1f - ly);
    float wd = (lx - x0f) * (ly - y0f);
    int ix0 = (int)x0f, iy0 = (int)y0f, ix1 = (int)x1f, iy1 = (int)y1f;
    int base = b * HW * C_ + g * CG;
    int ia = base + (iy0 * W_ + ix0) * C_;
    int ib = base + (iy1 * W_ + ix0) * C_;
    int ic = base + (iy0 * W_ + ix1) * C_;
    int id = base + (iy1 * W_ + ix1) * C_;
    float* tp8 = tab + (size_t)tid * 8;
    *(float4*)tp8 = make_float4(wa, wb, wc, wd);
    int4 iv = make_int4(ia, ib, ic, id);
    *(float4*)(tp8 + 4) = *(float4*)&iv;
}

// ---------------------------------------------------------------------------
// K4: fused sample + depthwise-3x3 + pointwise GEMM, ALL groups.
// 2-D tile: 4 rows x 16 cols of one image; window 6x18 (halo 1) -> 1.69x
// sample redundancy (vs 4.03x for 1-D 64-px tiles). Out-of-image window
// entries are written as ZERO at sampling time (== reference zero padding),
// so the depthwise phase is branch-free and uses sliding-window registers
// (3 LDS reads per output px instead of 9).
// ---------------------------------------------------------------------------
__global__ void __launch_bounds__(256) k_dwpw_all(
        const float* __restrict__ y, const float* __restrict__ tab,
        const float* __restrict__ w_dw, const float* __restrict__ b_dw,
        const float* __restrict__ w_pw, const float* __restrict__ b_pw,
        float* __restrict__ out) {
    __shared__ __hip_bfloat16 swin[WPOS][64];      // 13.5 KB
    __shared__ __align__(16) float ht [64][68];    // 17.4 KB
    __shared__ __align__(16) float wt_[64][68];    // 17.4 KB
    int g = blockIdx.y;
    int tile = blockIdx.x;              // b*144 + tr*6 + tc
    int b = tile / 144; int trem = tile - b * 144;
    int r0 = (trem / 6) * TM;
    int c0 = (trem - (trem / 6) * 6) * TN;
    int t = threadIdx.x;
    int lane = t & 63, wv = t >> 6;
    int tp = t >> 4, tf = t & 15;
    const float* wdwg = w_dw + (size_t)g * NPOS * KC;
    const float* bdwg = b_dw + (size_t)g * KC;
    const float* wpwg = w_pw + (size_t)g * KC * CG;
    const float* bpwg = b_pw + (size_t)g * CG;
    const float* tabg = tab + (size_t)g * NPIX * NPOS * 8;

    float acc[4][4] = {};
    for (int p = 0; p < NPOS; p++) {
        // stage pointwise-W chunk [64 k][64 f]
        #pragma unroll
        for (int i = 0; i < 16; i++) {
            int r = wv + i * 4;
            wt_[r][lane] = wpwg[(size_t)(p * 64 + r) * 64 + lane];
        }
        // sample the 6x18 window (zero outside the image)
        #pragma unroll 3
        for (int w = wv; w < WPOS; w += 4) {
            int wr = w / WC;
            int wc = w - wr * WC;
            int ny = r0 - 1 + wr, nx = c0 - 1 + wc;
            bool inb = ((unsigned)ny < (unsigned)H_) && ((unsigned)nx < (unsigned)W_);
            int nyc = min(max(ny, 0), H_ - 1);
            int nxc = min(max(nx, 0), W_ - 1);
            int npx = b * HW + nyc * W_ + nxc;
            const float* e = tabg + ((size_t)npx * NPOS + p) * 8;
            float4 w4 = *(const float4*)e;
            const int* ei = (const int*)(e + 4);
            float s = w4.x * y[ei[0] + lane] + w4.y * y[ei[1] + lane]
                    + w4.z * y[ei[2] + lane] + w4.w * y[ei[3] + lane];
            swin[w][lane] = __float2bfloat16(inb ? s : 0.f);
        }
        __syncthreads();
        // depthwise combine (branch-free, sliding window) -> ht
        int o = p * 64 + lane;
        float wd9[9];
        #pragma unroll
        for (int tap = 0; tap < 9; tap++) wd9[tap] = wdwg[tap * KC + o];
        float bd = bdwg[o];
        int base0 = (wv + 0) * WC, base1 = (wv + 1) * WC, base2 = (wv + 2) * WC;
        #define RD(pos) __bfloat162float(swin[pos][lane])
        float a0 = RD(base0 + 0), e0 = RD(base0 + 1);
        float a1 = RD(base1 + 0), e1 = RD(base1 + 1);
        float a2 = RD(base2 + 0), e2 = RD(base2 + 1);
        #pragma unroll
        for (int pc = 0; pc < TN; pc++) {
            float c0v = RD(base0 + pc + 2);
            float c1v = RD(base1 + pc + 2);
            float c2v = RD(base2 + pc + 2);
            float hv = bd
                + a0 * wd9[0] + e0 * wd9[1] + c0v * wd9[2]
                + a1 * wd9[3] + e1 * wd9[4] + c1v * wd9[5]
                + a2 * wd9[6] + e2 * wd9[7] + c2v * wd9[8];
            ht[wv * 16 + pc][lane] = hv;
            a0 = e0; e0 = c0v; a1 = e1; e1 = c1v; a2 = e2; e2 = c2v;
        }
        #undef RD
        __syncthreads();
        // GEMM chunk
        #pragma unroll 8
        for (int k = 0; k < 64; k++) {
            float4 bv = *(const float4*)&wt_[k][tf * 4];
            float a0g = ht[tp*4+0][k], a1g = ht[tp*4+1][k];
            float a2g = ht[tp*4+2][k], a3g = ht[tp*4+3][k];
            acc[0][0] += a0g*bv.x; acc[0][1] += a0g*bv.y; acc[0][2] += a0g*bv.z; acc[0][3] += a0g*bv.w;
            acc[1][0] += a1g*bv.x; acc[1][1] += a1g*bv.y; acc[1][2] += a1g*bv.z; acc[1][3] += a1g*bv.w;
            acc[2][0] += a2g*bv.x; acc[2][1] += a2g*bv.y; acc[2][2] += a2g*bv.z; acc[2][3] += a2g*bv.w;
            acc[3][0] += a3g*bv.x; acc[3][1] += a3g*bv.y; acc[3][2] += a3g*bv.z; acc[3][3] += a3g*bv.w;
        }
        __syncthreads();
    }
    float4 bb = *(const float4*)&bpwg[tf * 4];
    #pragma unroll
    for (int pi = 0; pi < 4; pi++) {
        int lp = tp * 4 + pi;
        int prow = lp >> 4, pcol = lp & 15;
        int px = b * HW + (r0 + prow) * W_ + (c0 + pcol);
        float4 v = make_float4(acc[pi][0] + bb.x, acc[pi][1] + bb.y,
                               acc[pi][2] + bb.z, acc[pi][3] + bb.w);
        *(float4*)&out[(size_t)px * C_ + g * CG + tf * 4] = v;
    }
}

// ---------------------------------------------------------------------------
// ws layout (floats): y 37.7MB | wt 166KB | off_all 10.6MB | tab 42.5MB
// ---------------------------------------------------------------------------
extern "C" void kernel_launch(void* const* d_in, const int* in_sizes, int n_in,
                              void* d_out, int out_size, void* d_ws, size_t ws_size,
                              hipStream_t stream) {
    const float* x      = (const float*)d_in[0];
    const float* w_init = (const float*)d_in[1];
    const float* b_init = (const float*)d_in[2];
    const float* w_off  = (const float*)d_in[3];
    const float* b_off  = (const float*)d_in[4];
    const float* w_dw   = (const float*)d_in[5];
    const float* b_dw   = (const float*)d_in[6];
    const float* w_pw   = (const float*)d_in[7];
    const float* b_pw   = (const float*)d_in[8];
    float* out = (float*)d_out;

    float* y       = (float*)d_ws;
    float* wt      = y       + (size_t)NPIX * C_;
    float* off_all = wt      + (size_t)G_ * 18 * NPOS * CG;
    float* tab     = off_all + (size_t)G_ * NPIX * 18;

    k_transpose_woff<<<(G_ * 18 * NPOS * CG + 255) / 256, 256, 0, stream>>>(w_off, wt);
    k_gemm_init<<<dim3(NPIX / 64, C_ / 64), 256, 0, stream>>>(x, w_init, b_init, y);
    k_offconv_all<<<dim3(1024, G_), 256, 0, stream>>>(y, wt, b_off, off_all);
    k_prep<<<(G_ * NPIX * NPOS + 255) / 256, 256, 0, stream>>>(off_all, tab);
    k_dwpw_all<<<dim3(576, G_), 256, 0, stream>>>(y, tab, w_dw, b_dw,
                                                  w_pw, b_pw, out);
}

// Round 5
// 620.758 us; speedup vs baseline: 8.4458x; 1.1570x over previous
//
#include <hip/hip_runtime.h>
#include <hip/hip_bf16.h>
#include <cstddef>

// Problem constants (B,H,W,C)=(4,96,96,256), G=4, K=3
#define B_   4
#define H_   96
#define W_   96
#define C_   256
#define G_   4
#define CG   64      // C/G
#define NPOS 9       // K*K
#define KC   576     // K*K*CG
#define HW   (H_*W_)      // 9216
#define NPIX (B_*H_*W_)   // 36864

// 2-D pixel tile for the fused kernel
#define TM 4
#define TN 16
#define WR 6          // TM+2
#define WC 18         // TN+2
#define WPOS 108      // WR*WC

typedef float f32x4 __attribute__((ext_vector_type(4)));
typedef short bf16x8 __attribute__((ext_vector_type(8)));

static __device__ __forceinline__ ushort f2bf(float f) {
    unsigned u = __float_as_uint(f);
    unsigned r = (u + 0x7fffu + ((u >> 16) & 1u)) >> 16;   // RNE
    return (ushort)r;
}
static __device__ __forceinline__ float bf2f(ushort u) {
    return __uint_as_float(((unsigned)u) << 16);
}

// ---------------------------------------------------------------------------
// K0: transpose w_off [G][3][3][CG][18] -> wt [G][18][9][CG]  (f32)
// ---------------------------------------------------------------------------
__global__ void k_transpose_woff(const float* __restrict__ w_off,
                                 float* __restrict__ wt) {
    int idx = blockIdx.x * 256 + threadIdx.x;
    const int total = G_ * 18 * NPOS * CG;
    if (idx >= total) return;
    int c = idx & 63;
    int r = idx >> 6;
    int nbr = r % NPOS; r /= NPOS;
    int oc  = r % 18;
    int g   = r / 18;
    wt[idx] = w_off[((size_t)(g * NPOS + nbr) * CG + c) * 18 + oc];
}

// ---------------------------------------------------------------------------
// Kc1: x (f32) -> split bf16 pair (hi, lo): hi=bf16(x), lo=bf16(x-hi)
// ---------------------------------------------------------------------------
__global__ void __launch_bounds__(256) k_cvt_x_split(
        const float* __restrict__ in, ushort* __restrict__ hi,
        ushort* __restrict__ lo, int n4) {
    int i = blockIdx.x * 256 + threadIdx.x;
    if (i >= n4) return;
    float4 a = *(const float4*)(in + (size_t)i * 4);
    ushort4 h, l;
    h.x = f2bf(a.x); l.x = f2bf(a.x - bf2f(h.x));
    h.y = f2bf(a.y); l.y = f2bf(a.y - bf2f(h.y));
    h.z = f2bf(a.z); l.z = f2bf(a.z - bf2f(h.z));
    h.w = f2bf(a.w); l.w = f2bf(a.w - bf2f(h.w));
    *(ushort4*)(hi + (size_t)i * 4) = h;
    *(ushort4*)(lo + (size_t)i * 4) = l;
}

// ---------------------------------------------------------------------------
// Kc2: w_init [k=256][co=256] -> wT split bf16 [co][k]
// ---------------------------------------------------------------------------
__global__ void k_cvt_wT_split(const float* __restrict__ w_init,
                               ushort* __restrict__ wTh,
                               ushort* __restrict__ wTl) {
    int idx = blockIdx.x * 256 + threadIdx.x;
    if (idx >= 256 * 256) return;
    int co = idx & 255, k = idx >> 8;
    float v = w_init[(size_t)k * 256 + co];
    ushort h = f2bf(v);
    wTh[(size_t)co * 256 + k] = h;
    wTl[(size_t)co * 256 + k] = f2bf(v - bf2f(h));
}

// ---------------------------------------------------------------------------
// Kc3: w_pw [g][k=576][f=64] -> wpwT split bf16 [g][f][k=576]
// ---------------------------------------------------------------------------
__global__ void k_cvt_wpwT_split(const float* __restrict__ w_pw,
                                 ushort* __restrict__ wpwTh,
                                 ushort* __restrict__ wpwTl) {
    int idx = blockIdx.x * 256 + threadIdx.x;
    if (idx >= G_ * KC * CG) return;
    int f = idx & 63;
    int k = (idx >> 6) % KC;
    int g = idx / (KC * CG);
    float v = w_pw[((size_t)g * KC + k) * CG + f];
    ushort h = f2bf(v);
    wpwTh[((size_t)g * CG + f) * KC + k] = h;
    wpwTl[((size_t)g * CG + f) * KC + k] = f2bf(v - bf2f(h));
}

// ---------------------------------------------------------------------------
// K1: init 1x1 conv via split-bf16 MFMA (Ah*Bh + Ah*Bl + Al*Bh ~ f32 exact).
// Tile 64px x 64co, K=256 in 4 chunks.
// ---------------------------------------------------------------------------
__global__ void __launch_bounds__(256) k_gemm_init_mfma(
        const ushort* __restrict__ xh, const ushort* __restrict__ xl,
        const ushort* __restrict__ wTh, const ushort* __restrict__ wTl,
        const float* __restrict__ bias, float* __restrict__ y) {
    __shared__ __align__(16) ushort ath[64][72], atl[64][72];
    __shared__ __align__(16) ushort bth[64][72], btl[64][72];
    int t = threadIdx.x;
    int px0 = blockIdx.x * 64, n0 = blockIdx.y * 64;
    int r = t >> 2, seg = (t & 3) * 16;
    int lane = t & 63, wv = t >> 6;
    int hl = lane & 15, qv = lane >> 4;
    f32x4 acc[4] = {};
    for (int kk = 0; kk < C_; kk += 64) {
        size_t xoff = (size_t)(px0 + r) * C_ + kk + seg;
        size_t woff = (size_t)(n0 + r) * C_ + kk + seg;
        const uint4* ph = (const uint4*)(xh + xoff);
        const uint4* pl = (const uint4*)(xl + xoff);
        const uint4* qh = (const uint4*)(wTh + woff);
        const uint4* ql = (const uint4*)(wTl + woff);
        uint4 a0 = ph[0], a1 = ph[1], b0 = pl[0], b1 = pl[1];
        uint4 c0 = qh[0], c1 = qh[1], d0 = ql[0], d1 = ql[1];
        *(uint4*)&ath[r][seg] = a0; *(uint4*)&ath[r][seg + 8] = a1;
        *(uint4*)&atl[r][seg] = b0; *(uint4*)&atl[r][seg + 8] = b1;
        *(uint4*)&bth[r][seg] = c0; *(uint4*)&bth[r][seg + 8] = c1;
        *(uint4*)&btl[r][seg] = d0; *(uint4*)&btl[r][seg + 8] = d1;
        __syncthreads();
        #pragma unroll
        for (int ks = 0; ks < 2; ks++) {
            bf16x8 ah_ = *(const bf16x8*)&ath[wv * 16 + hl][ks * 32 + qv * 8];
            bf16x8 al_ = *(const bf16x8*)&atl[wv * 16 + hl][ks * 32 + qv * 8];
            #pragma unroll
            for (int cg = 0; cg < 4; cg++) {
                bf16x8 bh_ = *(const bf16x8*)&bth[cg * 16 + hl][ks * 32 + qv * 8];
                bf16x8 bl_ = *(const bf16x8*)&btl[cg * 16 + hl][ks * 32 + qv * 8];
                acc[cg] = __builtin_amdgcn_mfma_f32_16x16x32_bf16(ah_, bh_, acc[cg], 0, 0, 0);
                acc[cg] = __builtin_amdgcn_mfma_f32_16x16x32_bf16(ah_, bl_, acc[cg], 0, 0, 0);
                acc[cg] = __builtin_amdgcn_mfma_f32_16x16x32_bf16(al_, bh_, acc[cg], 0, 0, 0);
            }
        }
        __syncthreads();
    }
    #pragma unroll
    for (int cg = 0; cg < 4; cg++) {
        int col = n0 + cg * 16 + hl;
        float bb = bias[col];
        #pragma unroll
        for (int rg = 0; rg < 4; rg++) {
            int row = px0 + wv * 16 + qv * 4 + rg;
            y[(size_t)row * C_ + col] = acc[cg][rg] + bb;
        }
    }
}

// ---------------------------------------------------------------------------
// K2: offsets 3x3 conv (64 -> 18), ALL groups (blockIdx.y = g).  (f32)
// ---------------------------------------------------------------------------
__global__ void __launch_bounds__(256) k_offconv_all(
        const float* __restrict__ y, const float* __restrict__ wt,
        const float* __restrict__ b_off, float* __restrict__ off_all) {
    int g = blockIdx.y;
    const float* wt_g = wt + (size_t)g * 18 * NPOS * CG;
    __shared__ float ws_[18 * NPOS * CG];
    for (int i = threadIdx.x; i < 18 * NPOS * CG; i += 256) ws_[i] = wt_g[i];
    __syncthreads();
    int lane = threadIdx.x & 63;
    float bo = b_off[g * 18 + (lane < 18 ? lane : 0)];
    int wv = blockIdx.x * 4 + (threadIdx.x >> 6);
    for (int px = wv; px < NPIX; px += 4096) {
        int b = px / HW; int rem = px - b * HW;
        int yy = rem / W_; int xx = rem - yy * W_;
        float partial[18];
        #pragma unroll
        for (int oc = 0; oc < 18; oc++) partial[oc] = 0.f;
        const float* yb = y + (size_t)b * HW * C_ + g * CG + lane;
        for (int di = 0; di < 3; di++) {
            int ny = yy + di - 1; if ((unsigned)ny >= H_) continue;
            for (int dj = 0; dj < 3; dj++) {
                int nx = xx + dj - 1; if ((unsigned)nx >= W_) continue;
                float yv = yb[(size_t)(ny * W_ + nx) * C_];
                int nbr = di * 3 + dj;
                #pragma unroll
                for (int oc = 0; oc < 18; oc++)
                    partial[oc] += yv * ws_[(oc * NPOS + nbr) * CG + lane];
            }
        }
        float res = 0.f;
        #pragma unroll
        for (int oc = 0; oc < 18; oc++) {
            float v = partial[oc];
            #pragma unroll
            for (int s = 32; s >= 1; s >>= 1) v += __shfl_xor(v, s, 64);
            if (lane == oc) res = v;
        }
        if (lane < 18) off_all[((size_t)g * NPIX + px) * 18 + lane] = res + bo;
    }
}

// ---------------------------------------------------------------------------
// K3: precompute bilinear weights + gather indices per (g, px, p).
// ---------------------------------------------------------------------------
__global__ void __launch_bounds__(256) k_prep(
        const float* __restrict__ off_all, float* __restrict__ tab) {
    int tid = blockIdx.x * 256 + threadIdx.x;
    const int total = G_ * NPIX * NPOS;
    if (tid >= total) return;
    int p = tid % NPOS; int rem = tid / NPOS;
    int px = rem % NPIX; int g = rem / NPIX;
    int b = px / HW; int r2 = px - b * HW;
    int yy = r2 / W_; int xx = r2 - yy * W_;
    float ox = off_all[(size_t)rem * 18 + 2 * p];
    float oy = off_all[(size_t)rem * 18 + 2 * p + 1];
    int di = p / 3, dj = p - di * 3;
    float lx = (float)(xx + dj - 1) + ox;
    float ly = (float)(yy + di - 1) + oy;
    lx = fminf(fmaxf(lx, 0.f), (float)(W_ - 1));
    ly = fminf(fmaxf(ly, 0.f), (float)(H_ - 1));
    float x0f = floorf(lx), y0f = floorf(ly);
    float x1f = fminf(x0f + 1.f, (float)(W_ - 1));
    float y1f = fminf(y0f + 1.f, (float)(H_ - 1));
    float wa = (x1f - lx) * (y1f - ly);
    float wb = (x1f - lx) * (ly - y0f);
    float wc = (lx - x0f) * (y1f - ly);
    float wd = (lx - x0f) * (ly - y0f);
    int ix0 = (int)x0f, iy0 = (int)y0f, ix1 = (int)x1f, iy1 = (int)y1f;
    int base = b * HW * C_ + g * CG;
    int ia = base + (iy0 * W_ + ix0) * C_;
    int ib = base + (iy1 * W_ + ix0) * C_;
    int ic = base + (iy0 * W_ + ix1) * C_;
    int id = base + (iy1 * W_ + ix1) * C_;
    float* tp8 = tab + (size_t)tid * 8;
    *(float4*)tp8 = make_float4(wa, wb, wc, wd);
    int4 iv = make_int4(ia, ib, ic, id);
    *(float4*)(tp8 + 4) = *(float4*)&iv;
}

// ---------------------------------------------------------------------------
// K4: fused sample + depthwise-3x3 + split-bf16-MFMA pointwise, ALL groups.
// 2-D tile 4x16 px, window 6x18. h and w_pw are kept as bf16 hi+lo pairs so
// the pointwise GEMM is ~f32-accurate; swin stays single-bf16 (R3-proven).
// ---------------------------------------------------------------------------
__global__ void __launch_bounds__(256) k_dwpw_all(
        const float* __restrict__ y, const float* __restrict__ tab,
        const float* __restrict__ w_dw, const float* __restrict__ b_dw,
        const ushort* __restrict__ wpwTh, const ushort* __restrict__ wpwTl,
        const float* __restrict__ b_pw, float* __restrict__ out) {
    __shared__ __align__(16) ushort swin[WPOS][64];          // 13.5 KB
    __shared__ __align__(16) ushort hth[64][72], htl[64][72];// 18 KB
    __shared__ __align__(16) ushort wth[64][72], wtl[64][72];// 18 KB
    int g = blockIdx.y;
    int tile = blockIdx.x;              // b*144 + tr*6 + tc
    int b = tile / 144; int trem = tile - b * 144;
    int r0 = (trem / 6) * TM;
    int c0 = (trem - (trem / 6) * 6) * TN;
    int t = threadIdx.x;
    int lane = t & 63, wv = t >> 6;
    int hl = lane & 15, qv = lane >> 4;
    int rr = t >> 2, seg = (t & 3) * 16;
    const float* wdwg = w_dw + (size_t)g * NPOS * KC;
    const float* bdwg = b_dw + (size_t)g * KC;
    const ushort* wpwgh = wpwTh + (size_t)g * CG * KC;
    const ushort* wpwgl = wpwTl + (size_t)g * CG * KC;
    const float* bpwg = b_pw + (size_t)g * CG;
    const float* tabg = tab + (size_t)g * NPIX * NPOS * 8;

    f32x4 acc[4] = {};
    for (int p = 0; p < NPOS; p++) {
        // stage pointwise-W chunk (split) transposed: wt*[f][k0..64)
        {
            const uint4* s0 = (const uint4*)(wpwgh + (size_t)rr * KC + p * 64 + seg);
            const uint4* s1 = (const uint4*)(wpwgl + (size_t)rr * KC + p * 64 + seg);
            uint4 w0 = s0[0], w1 = s0[1], w2 = s1[0], w3 = s1[1];
            *(uint4*)&wth[rr][seg]     = w0;
            *(uint4*)&wth[rr][seg + 8] = w1;
            *(uint4*)&wtl[rr][seg]     = w2;
            *(uint4*)&wtl[rr][seg + 8] = w3;
        }
        // sample the 6x18 window (zero outside the image)
        #pragma unroll 3
        for (int w = wv; w < WPOS; w += 4) {
            int wr = w / WC;
            int wc = w - wr * WC;
            int ny = r0 - 1 + wr, nx = c0 - 1 + wc;
            bool inb = ((unsigned)ny < (unsigned)H_) && ((unsigned)nx < (unsigned)W_);
            int nyc = min(max(ny, 0), H_ - 1);
            int nxc = min(max(nx, 0), W_ - 1);
            int npx = b * HW + nyc * W_ + nxc;
            const float* e = tabg + ((size_t)npx * NPOS + p) * 8;
            float4 w4 = *(const float4*)e;
            const int* ei = (const int*)(e + 4);
            float s = w4.x * y[ei[0] + lane] + w4.y * y[ei[1] + lane]
                    + w4.z * y[ei[2] + lane] + w4.w * y[ei[3] + lane];
            swin[w][lane] = f2bf(inb ? s : 0.f);
        }
        __syncthreads();
        // depthwise combine (branch-free, sliding window) -> ht hi/lo
        int o = p * 64 + lane;
        float wd9[9];
        #pragma unroll
        for (int tap = 0; tap < 9; tap++) wd9[tap] = wdwg[tap * KC + o];
        float bd = bdwg[o];
        int base0 = (wv + 0) * WC, base1 = (wv + 1) * WC, base2 = (wv + 2) * WC;
        #define RD(pos) bf2f(swin[pos][lane])
        float a0 = RD(base0 + 0), e0 = RD(base0 + 1);
        float a1 = RD(base1 + 0), e1 = RD(base1 + 1);
        float a2 = RD(base2 + 0), e2 = RD(base2 + 1);
        #pragma unroll
        for (int pc = 0; pc < TN; pc++) {
            float c0v = RD(base0 + pc + 2);
            float c1v = RD(base1 + pc + 2);
            float c2v = RD(base2 + pc + 2);
            float hv = bd
                + a0 * wd9[0] + e0 * wd9[1] + c0v * wd9[2]
                + a1 * wd9[3] + e1 * wd9[4] + c1v * wd9[5]
                + a2 * wd9[6] + e2 * wd9[7] + c2v * wd9[8];
            ushort hh = f2bf(hv);
            hth[wv * 16 + pc][lane] = hh;
            htl[wv * 16 + pc][lane] = f2bf(hv - bf2f(hh));
            a0 = e0; e0 = c0v; a1 = e1; e1 = c1v; a2 = e2; e2 = c2v;
        }
        #undef RD
        __syncthreads();
        // pointwise GEMM chunk via split MFMA
        #pragma unroll
        for (int ks = 0; ks < 2; ks++) {
            bf16x8 ah_ = *(const bf16x8*)&hth[wv * 16 + hl][ks * 32 + qv * 8];
            bf16x8 al_ = *(const bf16x8*)&htl[wv * 16 + hl][ks * 32 + qv * 8];
            #pragma unroll
            for (int cg = 0; cg < 4; cg++) {
                bf16x8 bh_ = *(const bf16x8*)&wth[cg * 16 + hl][ks * 32 + qv * 8];
                bf16x8 bl_ = *(const bf16x8*)&wtl[cg * 16 + hl][ks * 32 + qv * 8];
                acc[cg] = __builtin_amdgcn_mfma_f32_16x16x32_bf16(ah_, bh_, acc[cg], 0, 0, 0);
                acc[cg] = __builtin_amdgcn_mfma_f32_16x16x32_bf16(ah_, bl_, acc[cg], 0, 0, 0);
                acc[cg] = __builtin_amdgcn_mfma_f32_16x16x32_bf16(al_, bh_, acc[cg], 0, 0, 0);
            }
        }
        __syncthreads();
    }
    // epilogue: D row = qv*4+rg -> pixel col; wave wv -> pixel row r0+wv
    #pragma unroll
    for (int cg = 0; cg < 4; cg++) {
        int col = cg * 16 + hl;
        float bb = bpwg[col];
        #pragma unroll
        for (int rg = 0; rg < 4; rg++) {
            int pcol = qv * 4 + rg;
            int px = b * HW + (r0 + wv) * W_ + (c0 + pcol);
            out[(size_t)px * C_ + g * CG + col] = acc[cg][rg] + bb;
        }
    }
}

// ---------------------------------------------------------------------------
// ws layout: y 37.7MB | wt 166KB | off_all 10.6MB | tab 42.5MB |
//            xh/xl 18.9MB each | wTh/l 128KB each | wpwTh/l 288KB each
//            total ~121.6 MB
// ---------------------------------------------------------------------------
extern "C" void kernel_launch(void* const* d_in, const int* in_sizes, int n_in,
                              void* d_out, int out_size, void* d_ws, size_t ws_size,
                              hipStream_t stream) {
    const float* x      = (const float*)d_in[0];
    const float* w_init = (const float*)d_in[1];
    const float* b_init = (const float*)d_in[2];
    const float* w_off  = (const float*)d_in[3];
    const float* b_off  = (const float*)d_in[4];
    const float* w_dw   = (const float*)d_in[5];
    const float* b_dw   = (const float*)d_in[6];
    const float* w_pw   = (const float*)d_in[7];
    const float* b_pw   = (const float*)d_in[8];
    float* out = (float*)d_out;

    float* y       = (float*)d_ws;
    float* wt      = y       + (size_t)NPIX * C_;
    float* off_all = wt      + (size_t)G_ * 18 * NPOS * CG;
    float* tab     = off_all + (size_t)G_ * NPIX * 18;
    ushort* xh     = (ushort*)(tab + (size_t)G_ * NPIX * NPOS * 8);
    ushort* xl     = xh  + (size_t)NPIX * C_;
    ushort* wTh    = xl  + (size_t)NPIX * C_;
    ushort* wTl    = wTh + 256 * 256;
    ushort* wpwTh  = wTl + 256 * 256;
    ushort* wpwTl  = wpwTh + (size_t)G_ * KC * CG;

    k_transpose_woff<<<(G_ * 18 * NPOS * CG + 255) / 256, 256, 0, stream>>>(w_off, wt);
    k_cvt_x_split<<<(NPIX * C_ / 4 + 255) / 256, 256, 0, stream>>>(x, xh, xl, NPIX * C_ / 4);
    k_cvt_wT_split<<<(256 * 256 + 255) / 256, 256, 0, stream>>>(w_init, wTh, wTl);
    k_cvt_wpwT_split<<<(G_ * KC * CG + 255) / 256, 256, 0, stream>>>(w_pw, wpwTh, wpwTl);
    k_gemm_init_mfma<<<dim3(NPIX / 64, C_ / 64), 256, 0, stream>>>(xh, xl, wTh, wTl, b_init, y);
    k_offconv_all<<<dim3(1024, G_), 256, 0, stream>>>(y, wt, b_off, off_all);
    k_prep<<<(G_ * NPIX * NPOS + 255) / 256, 256, 0, stream>>>(off_all, tab);
    k_dwpw_all<<<dim3(576, G_), 256, 0, stream>>>(y, tab, w_dw, b_dw,
                                                  wpwTh, wpwTl, b_pw, out);
}